// Round 8
// baseline (924.550 us; speedup 1.0000x reference)
//
#include <hip/hip_runtime.h>
#include <hip/hip_bf16.h>

#define IN_DIM 256
#define HID    128
#define NSEG   320
#define MAXNORM 0.99999
#define NNODES 131072

typedef short bf16x8 __attribute__((ext_vector_type(8)));
typedef float f32x4  __attribute__((ext_vector_type(4)));

static __device__ __forceinline__ ushort f2b(float f) {
    uint u = __builtin_bit_cast(uint, f);
    uint r = 0x7FFFu + ((u >> 16) & 1u);      // round-to-nearest-even
    return (ushort)((u + r) >> 16);
}
static __device__ __forceinline__ float b2f_lo(uint v) {
    return __builtin_bit_cast(float, v << 16);
}
static __device__ __forceinline__ float b2f_hi(uint v) {
    return __builtin_bit_cast(float, v & 0xFFFF0000u);
}

// ---------------------------------------------------------------------------
// CSR build with pad-to-8 lists: count -> pad -> scan -> fill -> pad_fill
// ---------------------------------------------------------------------------
__global__ void count_edges_k(const int* __restrict__ dst, int* __restrict__ counts, int n) {
    int e = blockIdx.x * 256 + threadIdx.x;
    if (e < n) atomicAdd(&counts[dst[e]], 1);
}

__global__ void pad_counts_k(const int* __restrict__ counts, int* __restrict__ cpad, int n) {
    int i = blockIdx.x * 256 + threadIdx.x;
    if (i < n) cpad[i] = (counts[i] + 7) & ~7;
}

__global__ void scan_block_k(const int* __restrict__ in, int* __restrict__ out,
                             int* __restrict__ partials) {
    __shared__ int sh[256];
    int tid = threadIdx.x;
    int base = blockIdx.x * 1024 + tid * 4;
    int4 v = *(const int4*)&in[base];
    int s = v.x + v.y + v.z + v.w;
    sh[tid] = s;
    __syncthreads();
#pragma unroll
    for (int off = 1; off < 256; off <<= 1) {
        int t = (tid >= off) ? sh[tid - off] : 0;
        __syncthreads();
        sh[tid] += t;
        __syncthreads();
    }
    int excl = sh[tid] - s;
    int4 o;
    o.x = excl; o.y = excl + v.x; o.z = o.y + v.y; o.w = o.z + v.z;
    *(int4*)&out[base] = o;
    if (tid == 255) partials[blockIdx.x] = sh[255];
}

__global__ void scan_partials_k(int* __restrict__ partials, int n) {
    __shared__ int sh[1024];
    int tid = threadIdx.x;
    int v = (tid < n) ? partials[tid] : 0;
    sh[tid] = v;
    __syncthreads();
    for (int off = 1; off < blockDim.x; off <<= 1) {
        int t = (tid >= off) ? sh[tid - off] : 0;
        __syncthreads();
        sh[tid] += t;
        __syncthreads();
    }
    if (tid < n) partials[tid] = sh[tid] - v;
}

__global__ void add_base_k(int* __restrict__ offsets, const int* __restrict__ partials, int n) {
    int g = blockIdx.x * 256 + threadIdx.x;
    if (g < n) offsets[g] += partials[g >> 10];
}

__global__ void fill_edges_k(const int* __restrict__ src, const int* __restrict__ dst,
                             const int* __restrict__ offsets, int* __restrict__ cursor,
                             int* __restrict__ ssrc, int n) {
    int e = blockIdx.x * 256 + threadIdx.x;
    if (e < n) {
        int d = dst[e];
        int pos = atomicAdd(&cursor[d], 1);
        ssrc[offsets[d] + pos] = src[e];
    }
}

// fill pad slots [off+cnt, off+cpad) with the zero-row index NNODES
__global__ void pad_fill_k(const int* __restrict__ offsets, const int* __restrict__ counts,
                           const int* __restrict__ cpad, int* __restrict__ ssrc, int n) {
    int i = blockIdx.x * 256 + threadIdx.x;
    if (i < n) {
        int off = offsets[i], c = counts[i], cp = cpad[i];
        for (int j = c; j < cp; ++j) ssrc[off + j] = NNODES;
    }
}

// ---------------------------------------------------------------------------
// W pre-transpose+convert: W[K][128] f32 -> WT[128][K] bf16 (both weights)
// ---------------------------------------------------------------------------
__global__ void prep_wt_k(const float* __restrict__ w1, const float* __restrict__ w2,
                          ushort* __restrict__ w1t, ushort* __restrict__ w2t) {
    int id = blockIdx.x * 256 + threadIdx.x;
    if (id < 32768) {                      // W1: 256x128 -> 128x256
        int n = id >> 8, k = id & 255;
        w1t[n * 256 + k] = f2b(w1[k * 128 + n]);
    } else {                               // W2: 128x128 -> 128x128
        int id2 = id - 32768;
        int n = id2 >> 7, k = id2 & 127;
        w2t[n * 128 + k] = f2b(w2[k * 128 + n]);
    }
}

// ---------------------------------------------------------------------------
// bf16 MFMA GEMM: C[M][128](bf16) = A[M][K] @ B[K][128]   (verified r2-r5)
// ---------------------------------------------------------------------------
template<bool AF32>
__global__ __launch_bounds__(256) void gemm_k(const void* __restrict__ Ap,
                                              const ushort* __restrict__ BT,
                                              ushort* __restrict__ C, int K) {
    __shared__ __align__(16) char As[16384];   // [128][64] bf16, swizzled
    __shared__ __align__(16) char Bs[16384];
    const int tid = threadIdx.x;
    const int lane = tid & 63;
    const int wid = tid >> 6;
    const int wr = wid >> 1, wc = wid & 1;
    const int row0 = blockIdx.x * 128;
    f32x4 acc[4][4] = {};

    for (int k0 = 0; k0 < K; k0 += 64) {
        if (AF32) {
            const float* A = (const float*)Ap;
#pragma unroll
            for (int it = 0; it < 8; ++it) {
                int id = tid + it * 256;
                int r = id >> 4, c4 = (id & 15) * 4;
                float4 v = *(const float4*)&A[(size_t)(row0 + r) * K + k0 + c4];
                ushort4 h;
                h.x = f2b(v.x); h.y = f2b(v.y); h.z = f2b(v.z); h.w = f2b(v.w);
                *(ushort4*)(As + ((r * 128 + c4 * 2) ^ ((r & 7) << 4))) = h;
            }
        } else {
            const ushort* A = (const ushort*)Ap;
#pragma unroll
            for (int it = 0; it < 4; ++it) {
                int id = tid + it * 256;
                int r = id >> 3, c8 = (id & 7) * 8;
                bf16x8 v = *(const bf16x8*)&A[(size_t)(row0 + r) * K + k0 + c8];
                *(bf16x8*)(As + ((r * 128 + c8 * 2) ^ ((r & 7) << 4))) = v;
            }
        }
#pragma unroll
        for (int it = 0; it < 4; ++it) {
            int id = tid + it * 256;
            int n = id >> 3, c8 = (id & 7) * 8;
            bf16x8 v = *(const bf16x8*)&BT[(size_t)n * K + k0 + c8];
            *(bf16x8*)(Bs + ((n * 128 + c8 * 2) ^ ((n & 7) << 4))) = v;
        }
        __syncthreads();
#pragma unroll
        for (int kc = 0; kc < 2; ++kc) {
            bf16x8 af[4], bfr[4];
            int kb = (kc * 32 + (lane >> 4) * 8) * 2;
#pragma unroll
            for (int i = 0; i < 4; ++i) {
                int r = wr * 64 + i * 16 + (lane & 15);
                af[i] = *(const bf16x8*)(As + ((r * 128 + kb) ^ ((r & 7) << 4)));
                int n = wc * 64 + i * 16 + (lane & 15);
                bfr[i] = *(const bf16x8*)(Bs + ((n * 128 + kb) ^ ((n & 7) << 4)));
            }
#pragma unroll
            for (int i = 0; i < 4; ++i)
#pragma unroll
                for (int j = 0; j < 4; ++j)
                    acc[i][j] = __builtin_amdgcn_mfma_f32_16x16x32_bf16(
                        af[i], bfr[j], acc[i][j], 0, 0, 0);
        }
        __syncthreads();
    }
#pragma unroll
    for (int i = 0; i < 4; ++i)
#pragma unroll
        for (int j = 0; j < 4; ++j)
#pragma unroll
            for (int r = 0; r < 4; ++r) {
                int row = row0 + wr * 64 + i * 16 + (lane >> 4) * 4 + r;
                int col = wc * 64 + j * 16 + (lane & 15);
                C[(size_t)row * 128 + col] = f2b(acc[i][j][r]);
            }
}

// ---------------------------------------------------------------------------
// 4-rows-per-instruction gather. Wave per node; quadrant q=lane>>4 owns row
// j+q within each 4-row group; lane c=lane&15 loads dwordx4 (16B = 8 dims).
// Edge lists padded to x8 (dummy -> zeroed row NNODES): NO guards, NO
// shfl-broadcast, NO arrays. Indices are uniform int4 s_loads; per-quadrant
// row select is 2 cndmasks. 2 loads (= 8 edges) per iteration.
// ---------------------------------------------------------------------------
template<bool POOL>
__global__ __launch_bounds__(256) void gather8_k(
    const ushort* __restrict__ sup, const int* __restrict__ offsets,
    const int* __restrict__ cpad, const int* __restrict__ ssrc,
    const float* __restrict__ bias, const int* __restrict__ seg_ids,
    uint* __restrict__ hout, float* __restrict__ sums, int* __restrict__ seg_cnt) {
    const int node = __builtin_amdgcn_readfirstlane((blockIdx.x << 2) | (threadIdx.x >> 6));
    const int lane = threadIdx.x & 63;
    const int q = lane >> 4, c = lane & 15;
    const int off = __builtin_amdgcn_readfirstlane(offsets[node]);
    const int cp  = __builtin_amdgcn_readfirstlane(cpad[node]);
    const bool q1 = (q & 1) != 0, q2 = (q & 2) != 0;
    const ushort* supc = sup + c * 8;

    float a0 = 0.f, a1 = 0.f, a2 = 0.f, a3 = 0.f;
    float a4 = 0.f, a5 = 0.f, a6 = 0.f, a7 = 0.f;
    for (int j = 0; j < cp; j += 8) {
        const int4* sp = (const int4*)(ssrc + off + j);   // uniform -> s_load
        int4 ia = sp[0], ib = sp[1];
        int ra = q2 ? (q1 ? ia.w : ia.z) : (q1 ? ia.y : ia.x);
        int rb = q2 ? (q1 ? ib.w : ib.z) : (q1 ? ib.y : ib.x);
        uint4 v0 = *(const uint4*)(supc + (size_t)ra * 128);
        uint4 v1 = *(const uint4*)(supc + (size_t)rb * 128);
        a0 += b2f_lo(v0.x); a1 += b2f_hi(v0.x);
        a2 += b2f_lo(v0.y); a3 += b2f_hi(v0.y);
        a4 += b2f_lo(v0.z); a5 += b2f_hi(v0.z);
        a6 += b2f_lo(v0.w); a7 += b2f_hi(v0.w);
        a0 += b2f_lo(v1.x); a1 += b2f_hi(v1.x);
        a2 += b2f_lo(v1.y); a3 += b2f_hi(v1.y);
        a4 += b2f_lo(v1.z); a5 += b2f_hi(v1.z);
        a6 += b2f_lo(v1.w); a7 += b2f_hi(v1.w);
    }
    // reduce quadrant partials (each lane ends with full sum for its 8 dims)
    a0 += __shfl_xor(a0, 16); a0 += __shfl_xor(a0, 32);
    a1 += __shfl_xor(a1, 16); a1 += __shfl_xor(a1, 32);
    a2 += __shfl_xor(a2, 16); a2 += __shfl_xor(a2, 32);
    a3 += __shfl_xor(a3, 16); a3 += __shfl_xor(a3, 32);
    a4 += __shfl_xor(a4, 16); a4 += __shfl_xor(a4, 32);
    a5 += __shfl_xor(a5, 16); a5 += __shfl_xor(a5, 32);
    a6 += __shfl_xor(a6, 16); a6 += __shfl_xor(a6, 32);
    a7 += __shfl_xor(a7, 16); a7 += __shfl_xor(a7, 32);

    float4 b0 = *(const float4*)&bias[c * 8];
    float4 b1 = *(const float4*)&bias[c * 8 + 4];
    float h0 = tanhf(a0 + b0.x), h1 = tanhf(a1 + b0.y);
    float h2 = tanhf(a2 + b0.z), h3 = tanhf(a3 + b0.w);
    float h4 = tanhf(a4 + b1.x), h5 = tanhf(a5 + b1.y);
    float h6 = tanhf(a6 + b1.z), h7 = tanhf(a7 + b1.w);

    if (!POOL) {
        if (q == 0) {
            uint4 o;
            o.x = ((uint)f2b(h1) << 16) | (uint)f2b(h0);
            o.y = ((uint)f2b(h3) << 16) | (uint)f2b(h2);
            o.z = ((uint)f2b(h5) << 16) | (uint)f2b(h4);
            o.w = ((uint)f2b(h7) << 16) | (uint)f2b(h6);
            *(uint4*)&hout[(size_t)node * 64 + c * 4] = o;
        }
    } else {
        float ss = h0*h0 + h1*h1 + h2*h2 + h3*h3 + h4*h4 + h5*h5 + h6*h6 + h7*h7;
        ss += __shfl_xor(ss, 1); ss += __shfl_xor(ss, 2);
        ss += __shfl_xor(ss, 4); ss += __shfl_xor(ss, 8);
        double rr = sqrt((double)fmaxf(ss, 1e-15f));
        double m = fmin(rr, MAXNORM);
        float f = (float)(atanh(m) / rr);       // logmap0(proj(h)) scale
        if (q == 0) {
            int seg = seg_ids[node];
            atomicAdd(&sums[seg * 128 + c * 8 + 0], h0 * f);
            atomicAdd(&sums[seg * 128 + c * 8 + 1], h1 * f);
            atomicAdd(&sums[seg * 128 + c * 8 + 2], h2 * f);
            atomicAdd(&sums[seg * 128 + c * 8 + 3], h3 * f);
            atomicAdd(&sums[seg * 128 + c * 8 + 4], h4 * f);
            atomicAdd(&sums[seg * 128 + c * 8 + 5], h5 * f);
            atomicAdd(&sums[seg * 128 + c * 8 + 6], h6 * f);
            atomicAdd(&sums[seg * 128 + c * 8 + 7], h7 * f);
            if (lane == 0) atomicAdd(&seg_cnt[seg], 1);
        }
    }
}

// segment mean -> expmap0 -> proj
__global__ __launch_bounds__(64) void finalize_k(const float* __restrict__ sums,
                                                 const int* __restrict__ seg_cnt,
                                                 float* __restrict__ out) {
    int seg = blockIdx.x;
    int lane = threadIdx.x;
    float cnt = fmaxf((float)seg_cnt[seg], 1.0f);
    float ux = sums[seg * 128 + 2 * lane] / cnt;
    float uy = sums[seg * 128 + 2 * lane + 1] / cnt;
    float ss = ux * ux + uy * uy;
#pragma unroll
    for (int o = 32; o > 0; o >>= 1) ss += __shfl_xor(ss, o);
    double r = sqrt((double)fmaxf(ss, 1e-15f));
    double t = tanh(r);
    double fac = t / r;
    if (t > MAXNORM) fac = MAXNORM / r;
    float f = (float)fac;
    out[seg * 128 + 2 * lane] = ux * f;
    out[seg * 128 + 2 * lane + 1] = uy * f;
}

// ---------------------------------------------------------------------------
extern "C" void kernel_launch(void* const* d_in, const int* in_sizes, int n_in,
                              void* d_out, int out_size, void* d_ws, size_t ws_size,
                              hipStream_t stream) {
    const float* x   = (const float*)d_in[0];
    const int* src   = (const int*)d_in[1];
    const int* dst   = (const int*)d_in[2];
    const int* segid = (const int*)d_in[3];
    const float* W1  = (const float*)d_in[4];
    const float* b1  = (const float*)d_in[5];
    const float* W2  = (const float*)d_in[6];
    const float* b2  = (const float*)d_in[7];
    float* out       = (float*)d_out;

    const int N = in_sizes[3];          // 131072
    const int E = in_sizes[1];          // 2097152

    char* ws = (char*)d_ws;
    ushort* supA   = (ushort*)(ws);                      // (N+1)*128 bf16 = 32MB+256B
    uint*   h1u    = (uint*)(ws + 33555456);             // N*128 bf16 = 32MB
    ushort* h1     = (ushort*)h1u;
    int* ssrc      = (int*)(ws + 67109888);              // padded edges <= 3.1M -> 13MB
    int* counts    = (int*)(ws + 80740352);              // N ints
    int* cpad      = (int*)(ws + 81264640);              // N ints
    int* offsets   = (int*)(ws + 81788928);              // N ints
    int* cursor    = (int*)(ws + 82313216);              // N ints
    int* partials  = (int*)(ws + 82837504);              // 1KB
    float* sums    = (float*)(ws + 82838528);            // NSEG*128 f32
    int* seg_cnt   = (int*)(ws + 83002368);              // NSEG ints
    ushort* w1t    = (ushort*)(ws + 83003648);           // 128x256 bf16
    ushort* w2t    = (ushort*)(ws + 83069184);           // 128x128 bf16

    hipMemsetAsync(counts, 0, (size_t)N * 4, stream);
    hipMemsetAsync(cursor, 0, (size_t)N * 4, stream);
    hipMemsetAsync(sums, 0, (size_t)NSEG * 128 * 4, stream);
    hipMemsetAsync(seg_cnt, 0, (size_t)NSEG * 4, stream);
    hipMemsetAsync((char*)supA + (size_t)N * 256, 0, 256, stream);  // zero row

    const int eblocks = (E + 255) / 256;
    const int nblocks = (N + 255) / 256;
    const int nscan = N / 1024;

    prep_wt_k<<<192, 256, 0, stream>>>(W1, W2, w1t, w2t);

    count_edges_k<<<eblocks, 256, 0, stream>>>(dst, counts, E);
    pad_counts_k<<<nblocks, 256, 0, stream>>>(counts, cpad, N);
    scan_block_k<<<nscan, 256, 0, stream>>>(cpad, offsets, partials);
    scan_partials_k<<<1, nscan, 0, stream>>>(partials, nscan);
    add_base_k<<<nblocks, 256, 0, stream>>>(offsets, partials, N);
    fill_edges_k<<<eblocks, 256, 0, stream>>>(src, dst, offsets, cursor, ssrc, E);
    pad_fill_k<<<nblocks, 256, 0, stream>>>(offsets, counts, cpad, ssrc, N);

    // layer 1
    gemm_k<true><<<N / 128, 256, 0, stream>>>(x, w1t, supA, IN_DIM);
    gather8_k<false><<<N / 4, 256, 0, stream>>>(supA, offsets, cpad, ssrc, b1,
                                                segid, h1u, sums, seg_cnt);

    // layer 2 (fused pool: atomics hidden under gather latency, per r1-r4)
    gemm_k<false><<<N / 128, 256, 0, stream>>>(h1, w2t, supA, HID);
    gather8_k<true><<<N / 4, 256, 0, stream>>>(supA, offsets, cpad, ssrc, b2,
                                               segid, h1u, sums, seg_cnt);

    finalize_k<<<NSEG, 64, 0, stream>>>(sums, seg_cnt, out);
}

// Round 9
// 802.661 us; speedup vs baseline: 1.1519x; 1.1519x over previous
//
#include <hip/hip_runtime.h>
#include <hip/hip_bf16.h>

#define IN_DIM 256
#define HID    128
#define NSEG   320
#define MAXNORM 0.99999
#define NN     131072            // nodes
#define PANSH  14                // src>>14 -> panel 0..7 (16384 rows = 4MB bf16)
#define NITEM  32768             // 8 panels * 4096 dst-ranges of 32
#define NKEY   1048576           // key = (panel<<17) | dst

typedef short bf16x8 __attribute__((ext_vector_type(8)));
typedef float f32x4  __attribute__((ext_vector_type(4)));

static __device__ __forceinline__ ushort f2b(float f) {
    uint u = __builtin_bit_cast(uint, f);
    uint r = 0x7FFFu + ((u >> 16) & 1u);      // round-to-nearest-even
    return (ushort)((u + r) >> 16);
}
static __device__ __forceinline__ float b2f_lo(uint v) {
    return __builtin_bit_cast(float, v << 16);
}
static __device__ __forceinline__ float b2f_hi(uint v) {
    return __builtin_bit_cast(float, v & 0xFFFF0000u);
}

// ---------------------------------------------------------------------------
// Edge sort by key = (src_panel << 17) | dst  -> per-(panel,dst) runs
// ---------------------------------------------------------------------------
__global__ void count_edges_k(const int* __restrict__ src, const int* __restrict__ dst,
                              int* __restrict__ counts, int n) {
    int e = blockIdx.x * 256 + threadIdx.x;
    if (e < n) {
        int key = ((src[e] >> PANSH) << 17) | dst[e];
        atomicAdd(&counts[key], 1);
    }
}

__global__ void scan_block_k(const int* __restrict__ in, int* __restrict__ out,
                             int* __restrict__ partials) {
    __shared__ int sh[256];
    int tid = threadIdx.x;
    int base = blockIdx.x * 1024 + tid * 4;
    int4 v = *(const int4*)&in[base];
    int s = v.x + v.y + v.z + v.w;
    sh[tid] = s;
    __syncthreads();
#pragma unroll
    for (int off = 1; off < 256; off <<= 1) {
        int t = (tid >= off) ? sh[tid - off] : 0;
        __syncthreads();
        sh[tid] += t;
        __syncthreads();
    }
    int excl = sh[tid] - s;
    int4 o;
    o.x = excl; o.y = excl + v.x; o.z = o.y + v.y; o.w = o.z + v.z;
    *(int4*)&out[base] = o;
    if (tid == 255) partials[blockIdx.x] = sh[255];
}

__global__ void scan_partials_k(int* __restrict__ partials, int n) {
    __shared__ int sh[1024];
    int tid = threadIdx.x;
    int v = (tid < n) ? partials[tid] : 0;
    sh[tid] = v;
    __syncthreads();
    for (int off = 1; off < blockDim.x; off <<= 1) {
        int t = (tid >= off) ? sh[tid - off] : 0;
        __syncthreads();
        sh[tid] += t;
        __syncthreads();
    }
    if (tid < n) partials[tid] = sh[tid] - v;
}

__global__ void add_base_k(int* __restrict__ offsets, const int* __restrict__ partials, int n) {
    int g = blockIdx.x * 256 + threadIdx.x;
    if (g < n) offsets[g] += partials[g >> 10];
}

// packed edge = src(17b) | (dst&31)<<17
__global__ void fill_edges_k(const int* __restrict__ src, const int* __restrict__ dst,
                             const int* __restrict__ offsets, int* __restrict__ cursor,
                             uint* __restrict__ packed, int n) {
    int e = blockIdx.x * 256 + threadIdx.x;
    if (e < n) {
        int s = src[e], d = dst[e];
        int key = ((s >> PANSH) << 17) | d;
        int pos = atomicAdd(&cursor[key], 1);
        packed[offsets[key] + pos] = (uint)s | ((uint)(d & 31) << 17);
    }
}

// item im = (p<<12)|dr covers keys [(p<<17)|(dr<<5) .. +32); ioff[NITEM] = E
__global__ void extract_ioff_k(const int* __restrict__ offsets, int* __restrict__ ioff, int E) {
    int i = blockIdx.x * 256 + threadIdx.x;
    if (i < NITEM) ioff[i] = offsets[((i >> 12) << 17) | ((i & 4095) << 5)];
    if (i == NITEM) ioff[i] = E;
}

// ---------------------------------------------------------------------------
// Node->segment-rank (for atomic-free pooling)
// ---------------------------------------------------------------------------
__global__ void seg_count_k(const int* __restrict__ segid, int* __restrict__ scnt, int n) {
    int i = blockIdx.x * 256 + threadIdx.x;
    if (i < n) atomicAdd(&scnt[segid[i]], 1);
}

__global__ void seg_scan_k(const int* __restrict__ scnt, int* __restrict__ sstart, int n) {
    __shared__ int sh[512];
    int tid = threadIdx.x;
    int v = (tid < n) ? scnt[tid] : 0;
    sh[tid] = v;
    __syncthreads();
    for (int off = 1; off < 512; off <<= 1) {
        int t = (tid >= off) ? sh[tid - off] : 0;
        __syncthreads();
        sh[tid] += t;
        __syncthreads();
    }
    if (tid < n) sstart[tid] = sh[tid] - v;
    if (tid == 511) sstart[n] = sh[511];
}

__global__ void seg_fill_k(const int* __restrict__ segid, const int* __restrict__ sstart,
                           int* __restrict__ scur, int* __restrict__ rank, int n) {
    int i = blockIdx.x * 256 + threadIdx.x;
    if (i < n) {
        int s = segid[i];
        rank[i] = sstart[s] + atomicAdd(&scur[s], 1);
    }
}

// ---------------------------------------------------------------------------
// W pre-transpose+convert: W[K][128] f32 -> WT[128][K] bf16 (both weights)
// ---------------------------------------------------------------------------
__global__ void prep_wt_k(const float* __restrict__ w1, const float* __restrict__ w2,
                          ushort* __restrict__ w1t, ushort* __restrict__ w2t) {
    int id = blockIdx.x * 256 + threadIdx.x;
    if (id < 32768) {                      // W1: 256x128 -> 128x256
        int n = id >> 8, k = id & 255;
        w1t[n * 256 + k] = f2b(w1[k * 128 + n]);
    } else {                               // W2: 128x128 -> 128x128
        int id2 = id - 32768;
        int n = id2 >> 7, k = id2 & 127;
        w2t[n * 128 + k] = f2b(w2[k * 128 + n]);
    }
}

// ---------------------------------------------------------------------------
// bf16 MFMA GEMM: C[M][128](bf16) = A[M][K] @ B[K][128]   (verified r2-r8)
// ---------------------------------------------------------------------------
template<bool AF32>
__global__ __launch_bounds__(256) void gemm_k(const void* __restrict__ Ap,
                                              const ushort* __restrict__ BT,
                                              ushort* __restrict__ C, int K) {
    __shared__ __align__(16) char As[16384];   // [128][64] bf16, swizzled
    __shared__ __align__(16) char Bs[16384];
    const int tid = threadIdx.x;
    const int lane = tid & 63;
    const int wid = tid >> 6;
    const int wr = wid >> 1, wc = wid & 1;
    const int row0 = blockIdx.x * 128;
    f32x4 acc[4][4] = {};

    for (int k0 = 0; k0 < K; k0 += 64) {
        if (AF32) {
            const float* A = (const float*)Ap;
#pragma unroll
            for (int it = 0; it < 8; ++it) {
                int id = tid + it * 256;
                int r = id >> 4, c4 = (id & 15) * 4;
                float4 v = *(const float4*)&A[(size_t)(row0 + r) * K + k0 + c4];
                ushort4 h;
                h.x = f2b(v.x); h.y = f2b(v.y); h.z = f2b(v.z); h.w = f2b(v.w);
                *(ushort4*)(As + ((r * 128 + c4 * 2) ^ ((r & 7) << 4))) = h;
            }
        } else {
            const ushort* A = (const ushort*)Ap;
#pragma unroll
            for (int it = 0; it < 4; ++it) {
                int id = tid + it * 256;
                int r = id >> 3, c8 = (id & 7) * 8;
                bf16x8 v = *(const bf16x8*)&A[(size_t)(row0 + r) * K + k0 + c8];
                *(bf16x8*)(As + ((r * 128 + c8 * 2) ^ ((r & 7) << 4))) = v;
            }
        }
#pragma unroll
        for (int it = 0; it < 4; ++it) {
            int id = tid + it * 256;
            int n = id >> 3, c8 = (id & 7) * 8;
            bf16x8 v = *(const bf16x8*)&BT[(size_t)n * K + k0 + c8];
            *(bf16x8*)(Bs + ((n * 128 + c8 * 2) ^ ((n & 7) << 4))) = v;
        }
        __syncthreads();
#pragma unroll
        for (int kc = 0; kc < 2; ++kc) {
            bf16x8 af[4], bfr[4];
            int kb = (kc * 32 + (lane >> 4) * 8) * 2;
#pragma unroll
            for (int i = 0; i < 4; ++i) {
                int r = wr * 64 + i * 16 + (lane & 15);
                af[i] = *(const bf16x8*)(As + ((r * 128 + kb) ^ ((r & 7) << 4)));
                int n = wc * 64 + i * 16 + (lane & 15);
                bfr[i] = *(const bf16x8*)(Bs + ((n * 128 + kb) ^ ((n & 7) << 4)));
            }
#pragma unroll
            for (int i = 0; i < 4; ++i)
#pragma unroll
                for (int j = 0; j < 4; ++j)
                    acc[i][j] = __builtin_amdgcn_mfma_f32_16x16x32_bf16(
                        af[i], bfr[j], acc[i][j], 0, 0, 0);
        }
        __syncthreads();
    }
#pragma unroll
    for (int i = 0; i < 4; ++i)
#pragma unroll
        for (int j = 0; j < 4; ++j)
#pragma unroll
            for (int r = 0; r < 4; ++r) {
                int row = row0 + wr * 64 + i * 16 + (lane >> 4) * 4 + r;
                int col = wc * 64 + j * 16 + (lane & 15);
                C[(size_t)row * 128 + col] = f2b(acc[i][j][r]);
            }
}

// ---------------------------------------------------------------------------
// Phase A: per-(panel, 32-dst-range) item. blockIdx&7 = panel (XCD round-
// robin -> panel stays resident in that XCD's 4MB L2). One wave/item; LDS
// f32 [32 dsts][128 dims]; dl-sorted edges -> run-length register folding;
// epilogue streams bf16 partial rows via nontemporal stores.
// ---------------------------------------------------------------------------
__global__ __launch_bounds__(64) void phaseA_k(const uint* __restrict__ sup32,
                                               const uint* __restrict__ packed,
                                               const int* __restrict__ ioff,
                                               uint* __restrict__ partial) {
    __shared__ float acc[32][128];             // 16KB
    const int bid = blockIdx.x;
    const int p = bid & 7, dr = bid >> 3;
    const int lane = threadIdx.x;
#pragma unroll
    for (int i = lane; i < 4096; i += 64) ((float*)acc)[i] = 0.f;
    const int im = (p << 12) | dr;
    int a = __builtin_amdgcn_readfirstlane(ioff[im]);
    int b = __builtin_amdgcn_readfirstlane(ioff[im + 1]);
    float ax = 0.f, ay = 0.f;
    int prev = -1;
    int e = a;
    for (; e + 8 <= b; e += 8) {
        uint pe[8]; uint v[8];
#pragma unroll
        for (int t = 0; t < 8; ++t) pe[t] = packed[e + t];        // uniform s_loads
#pragma unroll
        for (int t = 0; t < 8; ++t)
            v[t] = sup32[(size_t)(pe[t] & 0x1FFFFu) * 64 + lane]; // L2-hit row dword
#pragma unroll
        for (int t = 0; t < 8; ++t) {
            int dl = (int)(pe[t] >> 17);
            if (dl != prev) {
                if (prev >= 0) { acc[prev][2 * lane] += ax; acc[prev][2 * lane + 1] += ay; }
                ax = 0.f; ay = 0.f; prev = dl;
            }
            ax += b2f_lo(v[t]); ay += b2f_hi(v[t]);
        }
    }
    for (; e < b; ++e) {
        uint pe = packed[e];
        uint v = sup32[(size_t)(pe & 0x1FFFFu) * 64 + lane];
        int dl = (int)(pe >> 17);
        if (dl != prev) {
            if (prev >= 0) { acc[prev][2 * lane] += ax; acc[prev][2 * lane + 1] += ay; }
            ax = 0.f; ay = 0.f; prev = dl;
        }
        ax += b2f_lo(v); ay += b2f_hi(v);
    }
    if (prev >= 0) { acc[prev][2 * lane] += ax; acc[prev][2 * lane + 1] += ay; }

    size_t obase = ((size_t)p * NN + (size_t)dr * 32) * 64 + lane;
#pragma unroll 4
    for (int d = 0; d < 32; ++d) {
        uint o = ((uint)f2b(acc[d][2 * lane + 1]) << 16) | (uint)f2b(acc[d][2 * lane]);
        __builtin_nontemporal_store(o, &partial[obase + (size_t)d * 64]);
    }
}

// ---------------------------------------------------------------------------
// Phase B1: h1 = tanh(sum_p partial[p] + b1), written in place of partial[0]
// ---------------------------------------------------------------------------
__global__ __launch_bounds__(256) void phaseB1_k(uint* __restrict__ partial,
                                                 const float* __restrict__ bias) {
    int i = blockIdx.x * 256 + threadIdx.x;    // grid covers NN*64 exactly
    float sx = 0.f, sy = 0.f;
#pragma unroll
    for (int p = 0; p < 8; ++p) {
        uint v = __builtin_nontemporal_load(&partial[(size_t)p * (NN * 64) + i]);
        sx += b2f_lo(v); sy += b2f_hi(v);
    }
    int l = i & 63;
    float2 bv = *(const float2*)&bias[2 * l];
    uint o = ((uint)f2b(tanhf(sy + bv.y)) << 16) | (uint)f2b(tanhf(sx + bv.x));
    partial[i] = o;                            // same element it read: no race
}

// ---------------------------------------------------------------------------
// Phase B2: h2 row = tanh(sum+b2); logmap0(proj) scale; write row PERMUTED
// into segment order (y[rank[node]]) -> pooling needs no atomics.
// ---------------------------------------------------------------------------
__global__ __launch_bounds__(256) void phaseB2_k(const uint* __restrict__ partial,
                                                 const float* __restrict__ bias,
                                                 const int* __restrict__ rank,
                                                 uint* __restrict__ y) {
    int node = (blockIdx.x << 2) | (threadIdx.x >> 6);
    int lane = threadIdx.x & 63;
    int i = node * 64 + lane;
    float sx = 0.f, sy = 0.f;
#pragma unroll
    for (int p = 0; p < 8; ++p) {
        uint v = __builtin_nontemporal_load(&partial[(size_t)p * (NN * 64) + i]);
        sx += b2f_lo(v); sy += b2f_hi(v);
    }
    float2 bv = *(const float2*)&bias[2 * lane];
    float hx = tanhf(sx + bv.x), hy = tanhf(sy + bv.y);
    float ss = hx * hx + hy * hy;
#pragma unroll
    for (int o = 32; o > 0; o >>= 1) ss += __shfl_xor(ss, o);
    double rr = sqrt((double)fmaxf(ss, 1e-15f));
    double m = fmin(rr, MAXNORM);
    float f = (float)(atanh(m) / rr);          // logmap0(proj(h)) scale
    uint o = ((uint)f2b(hy * f) << 16) | (uint)f2b(hx * f);
    y[(size_t)rank[node] * 64 + lane] = o;
}

// ---------------------------------------------------------------------------
// Pool: contiguous segment mean over y rows, then expmap0 -> proj. No atomics.
// ---------------------------------------------------------------------------
__global__ __launch_bounds__(256) void pool_k(const uint* __restrict__ y,
                                              const int* __restrict__ sstart,
                                              float* __restrict__ out) {
    __shared__ float red[4][128];
    int s = blockIdx.x;
    int wid = threadIdx.x >> 6, lane = threadIdx.x & 63;
    int a = sstart[s], b = sstart[s + 1];
    float sx = 0.f, sy = 0.f;
    for (int r = a + wid; r < b; r += 4) {
        uint v = y[(size_t)r * 64 + lane];
        sx += b2f_lo(v); sy += b2f_hi(v);
    }
    red[wid][2 * lane] = sx;
    red[wid][2 * lane + 1] = sy;
    __syncthreads();
    if (wid == 0) {
        sx = red[0][2 * lane] + red[1][2 * lane] + red[2][2 * lane] + red[3][2 * lane];
        sy = red[0][2 * lane + 1] + red[1][2 * lane + 1]
           + red[2][2 * lane + 1] + red[3][2 * lane + 1];
        float cnt = fmaxf((float)(b - a), 1.0f);
        float ux = sx / cnt, uy = sy / cnt;
        float ss = ux * ux + uy * uy;
#pragma unroll
        for (int o = 32; o > 0; o >>= 1) ss += __shfl_xor(ss, o);
        double r = sqrt((double)fmaxf(ss, 1e-15f));
        double t = tanh(r);
        double fac = t / r;
        if (t > MAXNORM) fac = MAXNORM / r;
        float f = (float)fac;
        out[s * 128 + 2 * lane] = ux * f;
        out[s * 128 + 2 * lane + 1] = uy * f;
    }
}

// ---------------------------------------------------------------------------
extern "C" void kernel_launch(void* const* d_in, const int* in_sizes, int n_in,
                              void* d_out, int out_size, void* d_ws, size_t ws_size,
                              hipStream_t stream) {
    const float* x   = (const float*)d_in[0];
    const int* src   = (const int*)d_in[1];
    const int* dst   = (const int*)d_in[2];
    const int* segid = (const int*)d_in[3];
    const float* W1  = (const float*)d_in[4];
    const float* b1  = (const float*)d_in[5];
    const float* W2  = (const float*)d_in[6];
    const float* b2  = (const float*)d_in[7];
    float* out       = (float*)d_out;

    const int N = in_sizes[3];          // 131072
    const int E = in_sizes[1];          // 2097152

    char* ws = (char*)d_ws;
    uint*   partial = (uint*)(ws);                       // 8 x 32MB bf16 partials
    ushort* h1      = (ushort*)partial;                  // phaseB1 output = partial[0]
    ushort* supA    = (ushort*)(ws + 268435456);         // 32MB [N][128] bf16
    uint*   sup32   = (uint*)supA;
    uint*   y32     = (uint*)supA;                       // y aliases supA (dead then)
    uint* packed    = (uint*)(ws + 301989888);           // 8MB
    int* counts     = (int*)(ws + 310378496);            // 4MB
    int* offsets    = (int*)(ws + 314572800);            // 4MB
    int* cursor     = (int*)(ws + 318767104);            // 4MB
    int* partials   = (int*)(ws + 322961408);            // 4KB
    int* ioff       = (int*)(ws + 322965504);            // 128KB+
    int* sstart     = (int*)(ws + 323097088);
    int* scnt       = (int*)(ws + 323098624);
    int* scur       = (int*)(ws + 323100160);
    int* rank       = (int*)(ws + 323101696);            // 512KB
    ushort* w1t     = (ushort*)(ws + 323625984);         // 64KB
    ushort* w2t     = (ushort*)(ws + 323691520);         // 32KB

    hipMemsetAsync(counts, 0, (size_t)NKEY * 4, stream);
    hipMemsetAsync(cursor, 0, (size_t)NKEY * 4, stream);
    hipMemsetAsync(scnt, 0, NSEG * 4, stream);
    hipMemsetAsync(scur, 0, NSEG * 4, stream);

    const int eblocks = (E + 255) / 256;

    prep_wt_k<<<192, 256, 0, stream>>>(W1, W2, w1t, w2t);

    // edge sort by (panel, dst)
    count_edges_k<<<eblocks, 256, 0, stream>>>(src, dst, counts, E);
    scan_block_k<<<NKEY / 1024, 256, 0, stream>>>(counts, offsets, partials);
    scan_partials_k<<<1, 1024, 0, stream>>>(partials, NKEY / 1024);
    add_base_k<<<NKEY / 256, 256, 0, stream>>>(offsets, partials, NKEY);
    fill_edges_k<<<eblocks, 256, 0, stream>>>(src, dst, offsets, cursor, packed, E);
    extract_ioff_k<<<(NITEM + 256) / 256, 256, 0, stream>>>(offsets, ioff, E);

    // node -> segment rank (for atomic-free pool)
    seg_count_k<<<N / 256, 256, 0, stream>>>(segid, scnt, N);
    seg_scan_k<<<1, 512, 0, stream>>>(scnt, sstart, NSEG);
    seg_fill_k<<<N / 256, 256, 0, stream>>>(segid, sstart, scur, rank, N);

    // layer 1
    gemm_k<true><<<N / 128, 256, 0, stream>>>(x, w1t, supA, IN_DIM);
    phaseA_k<<<NITEM, 64, 0, stream>>>(sup32, packed, ioff, partial);
    phaseB1_k<<<(N * 64) / 256, 256, 0, stream>>>(partial, b1);   // h1 -> partial[0]

    // layer 2
    gemm_k<false><<<N / 128, 256, 0, stream>>>(h1, w2t, supA, HID);
    phaseA_k<<<NITEM, 64, 0, stream>>>(sup32, packed, ioff, partial);
    phaseB2_k<<<N / 4, 256, 0, stream>>>(partial, b2, rank, y32);

    // pool (contiguous segment mean) + expmap0/proj
    pool_k<<<NSEG, 256, 0, stream>>>(y32, sstart, out);
}